// Round 9
// baseline (1688.519 us; speedup 1.0000x reference)
//
#include <hip/hip_runtime.h>

#define B_ 4
#define N_ 1024
#define F_ 128
#define R_ 16
#define E_ 65536
#define BN_ 4096
#define NB_ 512   // grid size of both persistent kernels

// ---------------------------------------------------------------------------
// Software grid barrier (generation based), mirroring __ockl_grid_sync:
//   release fence (all threads) -> barrier -> one-thread ticket protocol ->
//   barrier -> acquire fence (all threads).
// bar[0] = ticket count, bar[32] = generation (separate cachelines).
// Requires all NB_ blocks co-resident: grid=512, __launch_bounds__(256,2)
// -> 2 blocks/CU x 256 CU. Leader flips generation with RELEASE; waiters
// spin with ACQUIRE. Spin is BOUNDED (~100 ms) so a violated co-residency
// assumption degrades to a detectable wrong-output, never a hang.
// ---------------------------------------------------------------------------
__device__ __forceinline__ void gbar(int* bar) {
  __threadfence();          // release: publish this block's writes (agent scope)
  __syncthreads();
  if (threadIdx.x == 0) {
    int g = __hip_atomic_load(&bar[32], __ATOMIC_RELAXED, __HIP_MEMORY_SCOPE_AGENT);
    int t = __hip_atomic_fetch_add(&bar[0], 1, __ATOMIC_ACQ_REL, __HIP_MEMORY_SCOPE_AGENT);
    if (t == NB_ - 1) {
      __hip_atomic_store(&bar[0], 0, __ATOMIC_RELAXED, __HIP_MEMORY_SCOPE_AGENT);
      __hip_atomic_fetch_add(&bar[32], 1, __ATOMIC_RELEASE, __HIP_MEMORY_SCOPE_AGENT);
    } else {
      int spins = 0;
      while (__hip_atomic_load(&bar[32], __ATOMIC_ACQUIRE, __HIP_MEMORY_SCOPE_AGENT) == g) {
        __builtin_amdgcn_s_sleep(1);
        if (++spins > (1 << 22)) break;   // safety valve: fail loud, not hang
      }
    }
  }
  __syncthreads();
  __threadfence();          // acquire: all threads invalidate stale cached lines
}

// ============================================================================
// Kernel 1: CSR build + psi1 gather + psi1 GEMM (persistent, 512 blocks).
// ============================================================================
__global__ __launch_bounds__(256, 2) void prep_k(
    const float* __restrict__ xs, const float* __restrict__ xt,
    const int* __restrict__ eis, const int* __restrict__ eit,
    const float* __restrict__ W1s, const float* __restrict__ W1n,
    const float* __restrict__ b1,
    int* __restrict__ counts, int* __restrict__ cursor,
    int* __restrict__ offs, int* __restrict__ csr,
    float* __restrict__ aggs, float* __restrict__ aggt,
    float* __restrict__ hs, float* __restrict__ ht,
    int* __restrict__ bar) {
  const int bid = blockIdx.x, tid = threadIdx.x;
  const int gid = bid * 256 + tid;

  __shared__ int csum[256];
  __shared__ __align__(16) float sA[16][68];
  __shared__ __align__(16) float sB[16][68];

  // ---- Ph0: zero histograms (replaces hipMemsetAsync) ----
  if (gid < 2 * BN_) counts[gid] = 0;
  gbar(bar);

  // ---- Ph1: histogram of dst (131072 edges == 131072 threads) ----
  {
    int side = gid >> 16, e = gid & (E_ - 1);
    const int* ei = side ? eit : eis;
    atomicAdd(counts + side * BN_ + ei[E_ + e], 1);
  }
  gbar(bar);

  // ---- Ph2: exclusive scan per side (blocks 0,1 active) ----
  if (bid < 2) {
    const int* c = counts + bid * BN_;
    int* o = offs + bid * (BN_ + 1);
    int* cur = cursor + bid * BN_;
    int base = tid * 16;
    int local[16], sum = 0;
#pragma unroll
    for (int i = 0; i < 16; i++) { local[i] = sum; sum += c[base + i]; }
    csum[tid] = sum;
    __syncthreads();
    for (int d = 1; d < 256; d <<= 1) {
      int v = (tid >= d) ? csum[tid - d] : 0;
      __syncthreads();
      csum[tid] += v;
      __syncthreads();
    }
    int prev = (tid == 0) ? 0 : csum[tid - 1];
#pragma unroll
    for (int i = 0; i < 16; i++) {
      int off = prev + local[i];
      o[base + i] = off;
      cur[base + i] = off;
    }
    if (tid == 255) o[BN_] = csum[255];
  }
  gbar(bar);

  // ---- Ph3: fill src lists ----
  {
    int side = gid >> 16, e = gid & (E_ - 1);
    const int* ei = side ? eit : eis;
    int src = ei[e], dst = ei[E_ + e];
    int pos = atomicAdd(cursor + side * BN_ + dst, 1);
    csr[side * E_ + pos] = src;
  }
  gbar(bar);

  // ---- Ph4: psi1 neighbor gather (F=128), 8 node-pair roles per block ----
#pragma unroll 1
  for (int i = 0; i < 8; i++) {
    int role = i * 512 + bid;             // 4096 roles total
    int side = role >> 11, nblk = role & 2047;
    const float* x = side ? xt : xs;
    float* agg = side ? aggt : aggs;
    const int* cs = csr + side * E_;
    const int* of = offs + side * (BN_ + 1);
    int node = nblk * 2 + (tid >> 7);
    int ch = tid & 127;
    int j0 = of[node], j1 = of[node + 1];
    float a0 = 0.f, a1 = 0.f, a2 = 0.f, a3 = 0.f;
    int j = j0;
    for (; j + 3 < j1; j += 4) {
      int s0 = cs[j], s1 = cs[j + 1], s2 = cs[j + 2], s3 = cs[j + 3];
      a0 += x[(size_t)s0 * F_ + ch];
      a1 += x[(size_t)s1 * F_ + ch];
      a2 += x[(size_t)s2 * F_ + ch];
      a3 += x[(size_t)s3 * F_ + ch];
    }
    for (; j < j1; j++) a0 += x[(size_t)cs[j] * F_ + ch];
    agg[(size_t)node * F_ + ch] = (a0 + a1) + (a2 + a3);
  }
  gbar(bar);

  // ---- Ph5: h = relu(x@Ws + agg@Wn + b), 256 roles (64x64 tiles) ----
  if (bid < 256) {
    int side = bid >> 7;
    const float* x   = side ? xt   : xs;
    const float* agg = side ? aggt : aggs;
    float*       h   = side ? ht   : hs;
    int n0 = (bid & 1) * 64, m0 = ((bid >> 1) & 63) * 64;
    int tx = tid & 15, ty = tid >> 4;
    float acc[4][4] = {};
    for (int phase = 0; phase < 2; phase++) {
      const float* A  = phase ? agg : x;
      const float* Bw = phase ? W1n : W1s;
      for (int kb = 0; kb < F_; kb += 16) {
        int row = tid >> 2, k4 = (tid & 3) * 4;
        float4 va = *(const float4*)(A + (size_t)(m0 + row) * F_ + kb + k4);
        sA[k4 + 0][row] = va.x; sA[k4 + 1][row] = va.y;
        sA[k4 + 2][row] = va.z; sA[k4 + 3][row] = va.w;
        int k = tid >> 4, n4 = (tid & 15) * 4;
        *(float4*)&sB[k][n4] = *(const float4*)(Bw + (size_t)(kb + k) * F_ + n0 + n4);
        __syncthreads();
#pragma unroll
        for (int kk = 0; kk < 16; kk++) {
          float a[4], bb[4];
          *(float4*)a  = *(const float4*)&sA[kk][ty * 4];
          *(float4*)bb = *(const float4*)&sB[kk][tx * 4];
#pragma unroll
          for (int ii = 0; ii < 4; ii++)
#pragma unroll
            for (int jj = 0; jj < 4; jj++) acc[ii][jj] += a[ii] * bb[jj];
        }
        __syncthreads();
      }
    }
    float4 bv = *(const float4*)(b1 + n0 + tx * 4);
    float bj[4] = {bv.x, bv.y, bv.z, bv.w};
#pragma unroll
    for (int ii = 0; ii < 4; ii++) {
      int m = m0 + ty * 4 + ii;
      float4 o;
      o.x = fmaxf(acc[ii][0] + bj[0], 0.f); o.y = fmaxf(acc[ii][1] + bj[1], 0.f);
      o.z = fmaxf(acc[ii][2] + bj[2], 0.f); o.w = fmaxf(acc[ii][3] + bj[3], 0.f);
      *(float4*)(h + (size_t)m * F_ + n0 + tx * 4) = o;
    }
  }
}

// ============================================================================
// S_hat[b] = h_s[b] @ h_t[b]^T (NT), 128x128 tile, 8x8 micro — unchanged.
// ============================================================================
__global__ __launch_bounds__(256) void shat_gemm(
    const float* __restrict__ hs, const float* __restrict__ ht, float* __restrict__ S) {
  int b = blockIdx.z;
  int n0 = blockIdx.x * 128, m0 = blockIdx.y * 128;
  int tid = threadIdx.x, tx = tid & 15, ty = tid >> 4;
  __shared__ __align__(16) float sA[16][132];
  __shared__ __align__(16) float sB[16][132];
  float acc[8][8] = {};
  const float* Ag = hs + (size_t)(b * N_ + m0) * F_;
  const float* Bg = ht + (size_t)(b * N_ + n0) * F_;
  for (int kb = 0; kb < F_; kb += 16) {
#pragma unroll
    for (int l = 0; l < 2; l++) {
      int idx = tid + l * 256;
      int row = idx >> 2, k4 = (idx & 3) * 4;
      float4 va = *(const float4*)(Ag + (size_t)row * F_ + kb + k4);
      sA[k4 + 0][row] = va.x; sA[k4 + 1][row] = va.y;
      sA[k4 + 2][row] = va.z; sA[k4 + 3][row] = va.w;
      float4 vb = *(const float4*)(Bg + (size_t)row * F_ + kb + k4);
      sB[k4 + 0][row] = vb.x; sB[k4 + 1][row] = vb.y;
      sB[k4 + 2][row] = vb.z; sB[k4 + 3][row] = vb.w;
    }
    __syncthreads();
#pragma unroll
    for (int kk = 0; kk < 16; kk++) {
      float a[8], bb[8];
      *(float4*)&a[0]  = *(const float4*)&sA[kk][ty * 8];
      *(float4*)&a[4]  = *(const float4*)&sA[kk][ty * 8 + 4];
      *(float4*)&bb[0] = *(const float4*)&sB[kk][tx * 8];
      *(float4*)&bb[4] = *(const float4*)&sB[kk][tx * 8 + 4];
#pragma unroll
      for (int i = 0; i < 8; i++)
#pragma unroll
        for (int j = 0; j < 8; j++) acc[i][j] += a[i] * bb[j];
    }
    __syncthreads();
  }
#pragma unroll
  for (int i = 0; i < 8; i++) {
    size_t off = ((size_t)(b * N_ + m0 + ty * 8 + i)) * N_ + n0 + tx * 8;
    float4 o0 = {acc[i][0], acc[i][1], acc[i][2], acc[i][3]};
    float4 o1 = {acc[i][4], acc[i][5], acc[i][6], acc[i][7]};
    *(float4*)(S + off) = o0; *(float4*)(S + off + 4) = o1;
  }
}

// ============================================================================
// Kernel 2: softmax(S0) + both refinement steps (persistent, 512 blocks).
//   P0 softmax -> [P1 rt_part -> P2 reduce -> P3 gpsi2p -> P4 upd] x 2 steps
// P4: 8 s-rows per block, Pt[t][16] loaded once into registers and reused
// across the 8 rows (Pt4 L2 traffic 268 MB -> 33 MB per step).
// ============================================================================
__global__ __launch_bounds__(256, 2) void steps_k(
    float* __restrict__ Shat, float* __restrict__ S0, float* __restrict__ SL,
    const float* __restrict__ r_steps,
    const int* __restrict__ csr, const int* __restrict__ offs,
    const float* __restrict__ W2s, const float* __restrict__ W2n,
    const float* __restrict__ b2, const float* __restrict__ Wm1,
    const float* __restrict__ bm1, const float* __restrict__ Wm2,
    const float* __restrict__ bm2,
    float* __restrict__ part, float* __restrict__ rtb,
    float2* __restrict__ stats, float* __restrict__ Ps, float* __restrict__ Pt4,
    int* __restrict__ bar) {
  const int bid = blockIdx.x, tid = threadIdx.x;
  const int wave = tid >> 6, lane = tid & 63;

  __shared__ float wred[8];
  __shared__ float rsh[32][16];
  __shared__ float sstat[64];
  __shared__ float sWs[16][16], sWn[16][16], sWm[16][17];
  __shared__ float sv[16][17], sa[16][17], so[16][17];
  __shared__ float ssc[8][16];
  __shared__ float sred[8][4];

  // ---- P0: S0 = softmax(Shat) rows, 8 rows per block ----
#pragma unroll 1
  for (int i = 0; i < 8; i++) {
    int row = bid * 8 + i;
    float4 v = ((const float4*)(Shat + (size_t)row * N_))[tid];
    float m = fmaxf(fmaxf(v.x, v.y), fmaxf(v.z, v.w));
#pragma unroll
    for (int o = 32; o > 0; o >>= 1) m = fmaxf(m, __shfl_down(m, o, 64));
    if (lane == 0) wred[wave] = m;
    __syncthreads();
    m = fmaxf(fmaxf(wred[0], wred[1]), fmaxf(wred[2], wred[3]));
    float e0 = __expf(v.x - m), e1 = __expf(v.y - m);
    float e2 = __expf(v.z - m), e3 = __expf(v.w - m);
    float s = (e0 + e1) + (e2 + e3);
#pragma unroll
    for (int o = 32; o > 0; o >>= 1) s += __shfl_down(s, o, 64);
    if (lane == 0) wred[wave + 4] = s;   // disjoint slots: no extra sync needed
    __syncthreads();
    s = (wred[4] + wred[5]) + (wred[6] + wred[7]);
    float inv = 1.f / s;
    float4 o4 = {e0 * inv, e1 * inv, e2 * inv, e3 * inv};
    ((float4*)(S0 + (size_t)row * N_))[tid] = o4;
  }
  gbar(bar);

  for (int step = 0; step < 2; step++) {
    const float* rs = r_steps + (size_t)step * B_ * N_ * R_;

    // ---- P1: rt partials (roles == 512 blocks exactly) ----
    {
      int b = bid >> 7, c = (bid >> 2) & 31, t0 = (bid & 3) * 256;
      int s0 = c * 32;
      if (tid < 128) {
        int srow = tid >> 2, c4 = (tid & 3) * 4;
        float4 v = *(const float4*)(rs + ((size_t)(b * N_ + s0 + srow)) * R_ + c4);
        rsh[srow][c4] = v.x; rsh[srow][c4 + 1] = v.y;
        rsh[srow][c4 + 2] = v.z; rsh[srow][c4 + 3] = v.w;
      } else if (step && tid < 192) {
        sstat[tid - 128] = ((const float*)(stats + b * N_ + s0))[tid - 128];
      }
      __syncthreads();
      float acc[16] = {};
      const float* Ssrc = step ? Shat : S0;
      const float* Sp = Ssrc + ((size_t)(b * N_ + s0)) * N_ + t0 + tid;
      if (step) {
#pragma unroll
        for (int s = 0; s < 32; s++) {
          float svv = __expf(Sp[(size_t)s * N_] - sstat[2 * s]) * sstat[2 * s + 1];
#pragma unroll
          for (int r = 0; r < 16; r++) acc[r] += svv * rsh[s][r];
        }
      } else {
#pragma unroll
        for (int s = 0; s < 32; s++) {
          float svv = Sp[(size_t)s * N_];
#pragma unroll
          for (int r = 0; r < 16; r++) acc[r] += svv * rsh[s][r];
        }
      }
      float* o = part + ((size_t)((b * 32 + c) * N_) + t0 + tid) * R_;
      *(float4*)(o + 0)  = *(float4*)&acc[0];
      *(float4*)(o + 4)  = *(float4*)&acc[4];
      *(float4*)(o + 8)  = *(float4*)&acc[8];
      *(float4*)(o + 12) = *(float4*)&acc[12];
    }
    gbar(bar);

    // ---- P2: reduce 32 chunks -> rtb (65536 scalar jobs) ----
    {
      int g = bid * 256 + tid;
      if (g < B_ * N_ * R_) {
        int b = g >> 14, tr = g & 16383;
        const float* p = part + (size_t)b * (32 * N_ * R_) + tr;
        float a = 0.f;
#pragma unroll
        for (int c = 0; c < 32; c++) a += p[(size_t)c * (N_ * R_)];
        rtb[g] = a;
      }
    }
    gbar(bar);

    // ---- P3: fused gather + psi2 + @Wm1 (roles == 512 blocks exactly) ----
    {
      int side = bid >> 8, nblk = bid & 255;
      const float* v = side ? (const float*)rtb : rs;
      const int* cs = csr + side * E_;
      const int* of = offs + side * (BN_ + 1);
      int col = tid & 15, row = tid >> 4;
      int node = nblk * 16 + row;
      int j0 = of[node], j1 = of[node + 1];
      float a0 = 0.f, a1 = 0.f, a2 = 0.f, a3 = 0.f;
      int j = j0;
      for (; j + 3 < j1; j += 4) {
        int s0 = cs[j], s1 = cs[j + 1], s2 = cs[j + 2], s3 = cs[j + 3];
        a0 += v[(size_t)s0 * R_ + col];
        a1 += v[(size_t)s1 * R_ + col];
        a2 += v[(size_t)s2 * R_ + col];
        a3 += v[(size_t)s3 * R_ + col];
      }
      for (; j < j1; j++) a0 += v[(size_t)cs[j] * R_ + col];
      sWs[row][col] = W2s[row * 16 + col];
      sWn[row][col] = W2n[row * 16 + col];
      sWm[row][col] = Wm1[row * 16 + col];
      sv[row][col] = v[(size_t)node * R_ + col];
      sa[row][col] = (a0 + a1) + (a2 + a3);
      __syncthreads();
      float o = b2[col];
#pragma unroll
      for (int k = 0; k < 16; k++) o += sv[row][k] * sWs[k][col] + sa[row][k] * sWn[k][col];
      so[row][col] = fmaxf(o, 0.f);
      __syncthreads();
      float p = 0;
#pragma unroll
      for (int k = 0; k < 16; k++) p += so[row][k] * sWm[k][col];
      if (side) Pt4[((size_t)(col >> 2) * BN_ + node) * 4 + (col & 3)] = p;
      else      Ps[(size_t)node * R_ + col] = p;
    }
    gbar(bar);

    // ---- P4: row update, 8 s-rows per block, Pt in regs shared across rows ----
    {
      int b = bid >> 7;
      int s0 = (bid * 8) & (N_ - 1);
      int last = step;                       // step 1 writes SL, no Shat/stats
      if (tid < 128) {
        int i = tid >> 4, k = tid & 15;
        ssc[i][k] = Ps[((size_t)(b * N_ + s0 + i)) * R_ + k] + bm1[k];
      }
      float swr[16];
#pragma unroll
      for (int k = 0; k < 16; k++) swr[k] = Wm2[k];   // uniform -> scalar loads
      float bm2v = bm2[0];
      __syncthreads();
      float vals[8][4];
#pragma unroll
      for (int tile = 0; tile < 4; tile++) {
        int gt = b * N_ + tile * 256 + tid;
        float pt[16];
        *(float4*)&pt[0]  = *(const float4*)(Pt4 + ((size_t)0 * BN_ + gt) * 4);
        *(float4*)&pt[4]  = *(const float4*)(Pt4 + ((size_t)1 * BN_ + gt) * 4);
        *(float4*)&pt[8]  = *(const float4*)(Pt4 + ((size_t)2 * BN_ + gt) * 4);
        *(float4*)&pt[12] = *(const float4*)(Pt4 + ((size_t)3 * BN_ + gt) * 4);
#pragma unroll
        for (int i = 0; i < 8; i++) {
          size_t rowoff = ((size_t)(b * N_ + s0 + i)) * N_ + tile * 256 + tid;
          float sh = Shat[rowoff];
          float sum = bm2v;
#pragma unroll
          for (int k = 0; k < 16; k++) sum += fmaxf(ssc[i][k] - pt[k], 0.f) * swr[k];
          float vv = sh + sum;
          vals[i][tile] = vv;
          if (!last) Shat[rowoff] = vv;
        }
      }
      // per-row max
      float mrow[8], lrow[8];
#pragma unroll
      for (int i = 0; i < 8; i++) {
        float m = fmaxf(fmaxf(vals[i][0], vals[i][1]), fmaxf(vals[i][2], vals[i][3]));
#pragma unroll
        for (int o = 32; o > 0; o >>= 1) m = fmaxf(m, __shfl_down(m, o, 64));
        if (lane == 0) sred[i][wave] = m;
      }
      __syncthreads();
#pragma unroll
      for (int i = 0; i < 8; i++)
        mrow[i] = fmaxf(fmaxf(sred[i][0], sred[i][1]), fmaxf(sred[i][2], sred[i][3]));
      __syncthreads();
      // per-row expsum
#pragma unroll
      for (int i = 0; i < 8; i++) {
        float e = __expf(vals[i][0] - mrow[i]) + __expf(vals[i][1] - mrow[i])
                + __expf(vals[i][2] - mrow[i]) + __expf(vals[i][3] - mrow[i]);
#pragma unroll
        for (int o = 32; o > 0; o >>= 1) e += __shfl_down(e, o, 64);
        if (lane == 0) sred[i][wave] = e;
      }
      __syncthreads();
#pragma unroll
      for (int i = 0; i < 8; i++)
        lrow[i] = (sred[i][0] + sred[i][1]) + (sred[i][2] + sred[i][3]);
      if (!last) {
#pragma unroll
        for (int i = 0; i < 8; i++)
          if (tid == i) stats[b * N_ + s0 + i] = make_float2(mrow[i], 1.f / lrow[i]);
      } else {
#pragma unroll
        for (int i = 0; i < 8; i++) {
          float inv = 1.f / lrow[i];
          size_t rowoff = ((size_t)(b * N_ + s0 + i)) * N_;
#pragma unroll
          for (int tile = 0; tile < 4; tile++)
            SL[rowoff + tile * 256 + tid] = __expf(vals[i][tile] - mrow[i]) * inv;
        }
      }
    }
    if (step == 0) gbar(bar);
  }
}

extern "C" void kernel_launch(void* const* d_in, const int* in_sizes, int n_in,
                              void* d_out, int out_size, void* d_ws, size_t ws_size,
                              hipStream_t stream) {
  const float* x_s = (const float*)d_in[0];
  const int*   ei_s = (const int*)d_in[1];
  const float* x_t = (const float*)d_in[2];
  const int*   ei_t = (const int*)d_in[3];
  const float* W1s = (const float*)d_in[4];
  const float* W1n = (const float*)d_in[5];
  const float* b1  = (const float*)d_in[6];
  const float* W2s = (const float*)d_in[7];
  const float* W2n = (const float*)d_in[8];
  const float* b2  = (const float*)d_in[9];
  const float* Wm1 = (const float*)d_in[10];
  const float* bm1 = (const float*)d_in[11];
  const float* Wm2 = (const float*)d_in[12];
  const float* bm2 = (const float*)d_in[13];
  const float* r_steps = (const float*)d_in[14];

  float* out = (float*)d_out;
  float* S0 = out;                         // [4,1024,1024]
  float* SL = out + (size_t)B_ * N_ * N_;  // [4,1024,1024]

  float* ws = (float*)d_ws;
  float* agg_s = ws;                       // 524288   (dead after prep_k)
  float* agg_t = ws + 524288;              // 524288   (dead after prep_k)
  float* h_s   = ws + 1048576;             // 524288   (dead after shat_gemm)
  float* h_t   = ws + 1572864;             // 524288   (dead after shat_gemm)
  float* part  = ws;                       // 2097152 floats, reuses agg+h region
  float* Shat  = ws + 2097152;             // 4194304
  float* rtb   = ws + 6291456;             // 65536
  float2* stats = (float2*)(ws + 6356992); // 8192 floats (4096 float2)
  int*   bar   = (int*)(ws + 6365184);     // 64 ints (inside stats slot slack)
  float* Ps    = ws + 6488064;             // 65536
  float* Pt4   = ws + 6553600;             // 65536 (layout [4][4096][4])
  int* counts  = (int*)(ws + 6619136);     // 8192
  int* cursor  = (int*)(ws + 6627328);     // 8192
  int* offs    = (int*)(ws + 6635520);     // 8194 (2 x 4097)
  int* csr     = (int*)(ws + 6643720);     // 131072

  hipMemsetAsync(bar, 0, 64 * sizeof(int), stream);

  prep_k<<<NB_, 256, 0, stream>>>(x_s, x_t, ei_s, ei_t, W1s, W1n, b1,
                                  counts, cursor, offs, csr,
                                  agg_s, agg_t, h_s, h_t, bar);

  shat_gemm<<<dim3(8, 8, 4), 256, 0, stream>>>(h_s, h_t, Shat);

  steps_k<<<NB_, 256, 0, stream>>>(Shat, S0, SL, r_steps, csr, offs,
                                   W2s, W2n, b2, Wm1, bm1, Wm2, bm2,
                                   part, rtb, stats, Ps, Pt4, bar);
}

// Round 15
// 229.909 us; speedup vs baseline: 7.3443x; 7.3443x over previous
//
#include <hip/hip_runtime.h>

#define B_ 4
#define N_ 1024
#define F_ 128
#define R_ 16
#define E_ 65536
#define BN_ 4096

// ---------------- CSR build: histogram of dst (parallel, global atomics) ----------------
__global__ __launch_bounds__(256) void hist_k(
    const int* __restrict__ eis, const int* __restrict__ eit, int* __restrict__ counts) {
  const int* ei = blockIdx.y ? eit : eis;
  int* c = counts + blockIdx.y * BN_;
  int e = blockIdx.x * 256 + threadIdx.x;
  atomicAdd(c + ei[E_ + e], 1);
}

// ---------------- CSR build: exclusive scan (4096 = 256 threads x 16) ----------------
__global__ __launch_bounds__(256) void csr_scan(
    const int* __restrict__ counts, int* __restrict__ offs, int* __restrict__ cursor) {
  const int* c = counts + blockIdx.x * BN_;
  int* o = offs + blockIdx.x * (BN_ + 1);
  int* cur = cursor + blockIdx.x * BN_;
  int tid = threadIdx.x;
  int base = tid * 16;
  int local[16], sum = 0;
#pragma unroll
  for (int i = 0; i < 16; i++) { local[i] = sum; sum += c[base + i]; }
  __shared__ int csum[256];
  csum[tid] = sum;
  __syncthreads();
  for (int d = 1; d < 256; d <<= 1) {
    int v = (tid >= d) ? csum[tid - d] : 0;
    __syncthreads();
    csum[tid] += v;
    __syncthreads();
  }
  int prev = (tid == 0) ? 0 : csum[tid - 1];
#pragma unroll
  for (int i = 0; i < 16; i++) { int off = prev + local[i]; o[base + i] = off; cur[base + i] = off; }
  if (tid == 255) o[BN_] = csum[255];
}

// ---------------- CSR build: fill src lists ----------------
__global__ __launch_bounds__(256) void csr_fill(
    const int* __restrict__ eis, const int* __restrict__ eit,
    int* __restrict__ cursor, int* __restrict__ csr) {
  const int* ei = blockIdx.y ? eit : eis;
  int* cur = cursor + blockIdx.y * BN_;
  int* cs = csr + blockIdx.y * E_;
  int e = blockIdx.x * 256 + threadIdx.x;
  int src = ei[e], dst = ei[E_ + e];
  int pos = atomicAdd(cur + dst, 1);
  cs[pos] = src;
}

// ---------------- psi1 aggregation via gather, 4-way ILP ----------------
__global__ __launch_bounds__(256) void gather_f(
    const float* __restrict__ xs, const float* __restrict__ xt,
    const int* __restrict__ csr, const int* __restrict__ offs,
    float* __restrict__ aggs, float* __restrict__ aggt) {
  const float* x = blockIdx.y ? xt : xs;
  const int* cs = csr + blockIdx.y * E_;
  const int* of = offs + blockIdx.y * (BN_ + 1);
  float* agg = blockIdx.y ? aggt : aggs;
  int node = blockIdx.x * 2 + (threadIdx.x >> 7);
  int ch = threadIdx.x & 127;
  int j0 = of[node], j1 = of[node + 1];
  float a0 = 0.f, a1 = 0.f, a2 = 0.f, a3 = 0.f;
  int j = j0;
  for (; j + 3 < j1; j += 4) {
    int s0 = cs[j], s1 = cs[j + 1], s2 = cs[j + 2], s3 = cs[j + 3];
    a0 += x[(size_t)s0 * F_ + ch];
    a1 += x[(size_t)s1 * F_ + ch];
    a2 += x[(size_t)s2 * F_ + ch];
    a3 += x[(size_t)s3 * F_ + ch];
  }
  for (; j < j1; j++) a0 += x[(size_t)cs[j] * F_ + ch];
  agg[(size_t)node * F_ + ch] = (a0 + a1) + (a2 + a3);
}

// ------------- h = relu(x@Ws + agg@Wn + b), M=4096 N=128 K=128x2 -------------
__global__ __launch_bounds__(256) void psi1_gemm(
    const float* __restrict__ xs, const float* __restrict__ aggs,
    const float* __restrict__ xt, const float* __restrict__ aggt,
    const float* __restrict__ Ws, const float* __restrict__ Wn,
    const float* __restrict__ bias, float* __restrict__ hs, float* __restrict__ ht) {
  const float* x   = blockIdx.z ? xt   : xs;
  const float* agg = blockIdx.z ? aggt : aggs;
  float*       h   = blockIdx.z ? ht   : hs;
  int n0 = blockIdx.x * 64, m0 = blockIdx.y * 64;
  int tid = threadIdx.x, tx = tid & 15, ty = tid >> 4;
  __shared__ __align__(16) float sA[16][68];
  __shared__ __align__(16) float sB[16][68];
  float acc[4][4] = {};
  for (int phase = 0; phase < 2; phase++) {
    const float* A  = phase ? agg : x;
    const float* Bw = phase ? Wn  : Ws;
    for (int kb = 0; kb < F_; kb += 16) {
      int row = tid >> 2, k4 = (tid & 3) * 4;
      float4 va = *(const float4*)(A + (size_t)(m0 + row) * F_ + kb + k4);
      sA[k4 + 0][row] = va.x; sA[k4 + 1][row] = va.y;
      sA[k4 + 2][row] = va.z; sA[k4 + 3][row] = va.w;
      int k = tid >> 4, n4 = (tid & 15) * 4;
      *(float4*)&sB[k][n4] = *(const float4*)(Bw + (size_t)(kb + k) * F_ + n0 + n4);
      __syncthreads();
#pragma unroll
      for (int kk = 0; kk < 16; kk++) {
        float a[4], bb[4];
        *(float4*)a  = *(const float4*)&sA[kk][ty * 4];
        *(float4*)bb = *(const float4*)&sB[kk][tx * 4];
#pragma unroll
        for (int i = 0; i < 4; i++)
#pragma unroll
          for (int j = 0; j < 4; j++) acc[i][j] += a[i] * bb[j];
      }
      __syncthreads();
    }
  }
  float4 bv = *(const float4*)(bias + n0 + tx * 4);
  float bj[4] = {bv.x, bv.y, bv.z, bv.w};
#pragma unroll
  for (int i = 0; i < 4; i++) {
    int m = m0 + ty * 4 + i;
    float4 o;
    o.x = fmaxf(acc[i][0] + bj[0], 0.f); o.y = fmaxf(acc[i][1] + bj[1], 0.f);
    o.z = fmaxf(acc[i][2] + bj[2], 0.f); o.w = fmaxf(acc[i][3] + bj[3], 0.f);
    *(float4*)(h + (size_t)m * F_ + n0 + tx * 4) = o;
  }
}

// ---------- S_hat[b] = h_s[b] @ h_t[b]^T  (NT), 128x128 tile, 8x8 micro ----------
__global__ __launch_bounds__(256) void shat_gemm(
    const float* __restrict__ hs, const float* __restrict__ ht, float* __restrict__ S) {
  int b = blockIdx.z;
  int n0 = blockIdx.x * 128, m0 = blockIdx.y * 128;
  int tid = threadIdx.x, tx = tid & 15, ty = tid >> 4;
  __shared__ __align__(16) float sA[16][132];
  __shared__ __align__(16) float sB[16][132];
  float acc[8][8] = {};
  const float* Ag = hs + (size_t)(b * N_ + m0) * F_;
  const float* Bg = ht + (size_t)(b * N_ + n0) * F_;
  for (int kb = 0; kb < F_; kb += 16) {
#pragma unroll
    for (int l = 0; l < 2; l++) {
      int idx = tid + l * 256;
      int row = idx >> 2, k4 = (idx & 3) * 4;
      float4 va = *(const float4*)(Ag + (size_t)row * F_ + kb + k4);
      sA[k4 + 0][row] = va.x; sA[k4 + 1][row] = va.y;
      sA[k4 + 2][row] = va.z; sA[k4 + 3][row] = va.w;
      float4 vb = *(const float4*)(Bg + (size_t)row * F_ + kb + k4);
      sB[k4 + 0][row] = vb.x; sB[k4 + 1][row] = vb.y;
      sB[k4 + 2][row] = vb.z; sB[k4 + 3][row] = vb.w;
    }
    __syncthreads();
#pragma unroll
    for (int kk = 0; kk < 16; kk++) {
      float a[8], bb[8];
      *(float4*)&a[0]  = *(const float4*)&sA[kk][ty * 8];
      *(float4*)&a[4]  = *(const float4*)&sA[kk][ty * 8 + 4];
      *(float4*)&bb[0] = *(const float4*)&sB[kk][tx * 8];
      *(float4*)&bb[4] = *(const float4*)&sB[kk][tx * 8 + 4];
#pragma unroll
      for (int i = 0; i < 8; i++)
#pragma unroll
        for (int j = 0; j < 8; j++) acc[i][j] += a[i] * bb[j];
    }
    __syncthreads();
  }
#pragma unroll
  for (int i = 0; i < 8; i++) {
    size_t off = ((size_t)(b * N_ + m0 + ty * 8 + i)) * N_ + n0 + tx * 8;
    float4 o0 = {acc[i][0], acc[i][1], acc[i][2], acc[i][3]};
    float4 o1 = {acc[i][4], acc[i][5], acc[i][6], acc[i][7]};
    *(float4*)(S + off) = o0; *(float4*)(S + off + 4) = o1;
  }
}

// ---------------- row softmax over N=1024, one block per row ----------------
__global__ __launch_bounds__(256) void softmax_row(
    const float* __restrict__ in, float* __restrict__ out) {
  int row = blockIdx.x;
  float4 v = ((const float4*)(in + (size_t)row * N_))[threadIdx.x];
  float m = fmaxf(fmaxf(v.x, v.y), fmaxf(v.z, v.w));
#pragma unroll
  for (int o = 32; o > 0; o >>= 1) m = fmaxf(m, __shfl_down(m, o, 64));
  __shared__ float rmax[4], rsum[4];
  int wave = threadIdx.x >> 6, lane = threadIdx.x & 63;
  if (lane == 0) rmax[wave] = m;
  __syncthreads();
  m = fmaxf(fmaxf(rmax[0], rmax[1]), fmaxf(rmax[2], rmax[3]));
  float e0 = __expf(v.x - m), e1 = __expf(v.y - m);
  float e2 = __expf(v.z - m), e3 = __expf(v.w - m);
  float s = e0 + e1 + e2 + e3;
#pragma unroll
  for (int o = 32; o > 0; o >>= 1) s += __shfl_down(s, o, 64);
  if (lane == 0) rsum[wave] = s;
  __syncthreads();
  s = rsum[0] + rsum[1] + rsum[2] + rsum[3];
  float inv = 1.f / s;
  float4 o4 = {e0 * inv, e1 * inv, e2 * inv, e3 * inv};
  ((float4*)(out + (size_t)row * N_))[threadIdx.x] = o4;
}

// ---- r_t partial: part[b][c][t][r] = sum_{s in chunk c} S[b,s,t]*r_s[b,s,r] ----
template <bool EXP>
__global__ __launch_bounds__(256) void rt_part_k(
    const float* __restrict__ S, const float2* __restrict__ stats,
    const float* __restrict__ rs, float* __restrict__ part) {
  int b = blockIdx.z, c = blockIdx.y, t0 = blockIdx.x * 256;
  int tid = threadIdx.x;
  int s0 = c * 32;
  __shared__ float rsh[32][16];
  __shared__ float sstat[64];
  if (tid < 128) {
    int srow = tid >> 2, c4 = (tid & 3) * 4;
    float4 v = *(const float4*)(rs + ((size_t)(b * N_ + s0 + srow)) * R_ + c4);
    rsh[srow][c4] = v.x; rsh[srow][c4 + 1] = v.y;
    rsh[srow][c4 + 2] = v.z; rsh[srow][c4 + 3] = v.w;
  } else if (EXP && tid < 192) {
    sstat[tid - 128] = ((const float*)(stats + b * N_ + s0))[tid - 128];
  }
  __syncthreads();
  float acc[16] = {};
  const float* Sp = S + ((size_t)(b * N_ + s0)) * N_ + t0 + tid;
#pragma unroll
  for (int s = 0; s < 32; s++) {
    float sv = Sp[(size_t)s * N_];
    if (EXP) sv = __expf(sv - sstat[2 * s]) * sstat[2 * s + 1];
#pragma unroll
    for (int r = 0; r < 16; r++) acc[r] += sv * rsh[s][r];
  }
  float* o = part + ((size_t)((b * 32 + c) * N_) + t0 + tid) * R_;
  *(float4*)(o + 0)  = *(float4*)&acc[0];
  *(float4*)(o + 4)  = *(float4*)&acc[4];
  *(float4*)(o + 8)  = *(float4*)&acc[8];
  *(float4*)(o + 12) = *(float4*)&acc[12];
}

// ---- r_t reduce over 32 chunks ----
__global__ __launch_bounds__(256) void rt_reduce(
    const float* __restrict__ part, float* __restrict__ rt) {
  int gid = blockIdx.x * 256 + threadIdx.x;   // 16384 float4 outputs
  int b = gid >> 12, tr = gid & 4095;
  const float* p = part + (size_t)b * (32 * N_ * R_) + (size_t)tr * 4;
  float4 acc = {0.f, 0.f, 0.f, 0.f};
#pragma unroll
  for (int c = 0; c < 32; c++) {
    float4 v = *(const float4*)(p + (size_t)c * (N_ * R_));
    acc.x += v.x; acc.y += v.y; acc.z += v.z; acc.w += v.w;
  }
  ((float4*)rt)[gid] = acc;
}

// ---- fused gather + psi2 + @Wm1: P = relu(v@W2s + (gather v)@W2n + b2) @ Wm1 ----
__global__ __launch_bounds__(256) void gpsi2p(
    const float* __restrict__ vs, const float* __restrict__ vt,
    const int* __restrict__ csr, const int* __restrict__ offs,
    const float* __restrict__ W2s, const float* __restrict__ W2n,
    const float* __restrict__ b2, const float* __restrict__ Wm1,
    float* __restrict__ Ps, float* __restrict__ Pt4) {
  const float* v = blockIdx.y ? vt : vs;
  const int* cs = csr + blockIdx.y * E_;
  const int* of = offs + blockIdx.y * (BN_ + 1);
  int col = threadIdx.x & 15, row = threadIdx.x >> 4;
  int node = blockIdx.x * 16 + row;
  int j0 = of[node], j1 = of[node + 1];
  float a0 = 0.f, a1 = 0.f, a2 = 0.f, a3 = 0.f;
  int j = j0;
  for (; j + 3 < j1; j += 4) {
    int s0 = cs[j], s1 = cs[j + 1], s2 = cs[j + 2], s3 = cs[j + 3];
    a0 += v[(size_t)s0 * R_ + col];
    a1 += v[(size_t)s1 * R_ + col];
    a2 += v[(size_t)s2 * R_ + col];
    a3 += v[(size_t)s3 * R_ + col];
  }
  for (; j < j1; j++) a0 += v[(size_t)cs[j] * R_ + col];
  __shared__ float sWs[16][16], sWn[16][16], sWm[16][17];
  __shared__ float sv[16][17], sa[16][17], so[16][17];
  sWs[row][col] = W2s[row * 16 + col];
  sWn[row][col] = W2n[row * 16 + col];
  sWm[row][col] = Wm1[row * 16 + col];
  sv[row][col] = v[(size_t)node * R_ + col];
  sa[row][col] = (a0 + a1) + (a2 + a3);
  __syncthreads();
  float o = b2[col];
#pragma unroll
  for (int k = 0; k < 16; k++) o += sv[row][k] * sWs[k][col] + sa[row][k] * sWn[k][col];
  so[row][col] = fmaxf(o, 0.f);
  __syncthreads();
  float p = 0;
#pragma unroll
  for (int k = 0; k < 16; k++) p += so[row][k] * sWm[k][col];
  if (blockIdx.y) {
    Pt4[((size_t)(col >> 2) * BN_ + node) * 4 + (col & 3)] = p;
  } else {
    Ps[(size_t)node * R_ + col] = p;
  }
}

// ---- row update, 8 s-rows per block: Pt[t][16] loaded ONCE into registers and
// reused across the 8 rows (Pt4 L2 traffic 268 MB -> 33 MB per step).
// LAST=0: write updated Shat + row stats (max, 1/sumexp).
// LAST=1: don't write Shat; write SL = softmax(updated row) directly.
template <int LAST>
__device__ __forceinline__ void upd_row8_body(
    float* __restrict__ Shat, const float* __restrict__ Ps, const float* __restrict__ Pt4,
    const float* __restrict__ bm1, const float* __restrict__ Wm2,
    const float* __restrict__ bm2, float2* __restrict__ stats, float* __restrict__ SL) {
  int b = blockIdx.y, s0 = blockIdx.x * 8;
  int tid = threadIdx.x;
  int wave = tid >> 6, lane = tid & 63;
  __shared__ float ssc[8][16];   // ssc[i][k] = Ps[s0+i][k] + bm1[k]
  __shared__ float sred[8][4];
  if (tid < 128) {
    int i = tid >> 4, k = tid & 15;
    ssc[i][k] = Ps[((size_t)(b * N_ + s0 + i)) * R_ + k] + bm1[k];
  }
  float swr[16];
#pragma unroll
  for (int k = 0; k < 16; k++) swr[k] = Wm2[k];   // uniform -> scalar loads
  float bm2v = bm2[0];
  __syncthreads();
  float vals[8][4];
#pragma unroll
  for (int tile = 0; tile < 4; tile++) {
    int gt = b * N_ + tile * 256 + tid;
    float pt[16];
    *(float4*)&pt[0]  = *(const float4*)(Pt4 + ((size_t)0 * BN_ + gt) * 4);
    *(float4*)&pt[4]  = *(const float4*)(Pt4 + ((size_t)1 * BN_ + gt) * 4);
    *(float4*)&pt[8]  = *(const float4*)(Pt4 + ((size_t)2 * BN_ + gt) * 4);
    *(float4*)&pt[12] = *(const float4*)(Pt4 + ((size_t)3 * BN_ + gt) * 4);
#pragma unroll
    for (int i = 0; i < 8; i++) {
      size_t rowoff = ((size_t)(b * N_ + s0 + i)) * N_ + tile * 256 + tid;
      float sh = Shat[rowoff];
      float sum = bm2v;
#pragma unroll
      for (int k = 0; k < 16; k++) sum += fmaxf(ssc[i][k] - pt[k], 0.f) * swr[k];
      float vv = sh + sum;
      vals[i][tile] = vv;
      if (!LAST) Shat[rowoff] = vv;
    }
  }
  // per-row max
  float mrow[8], lrow[8];
#pragma unroll
  for (int i = 0; i < 8; i++) {
    float m = fmaxf(fmaxf(vals[i][0], vals[i][1]), fmaxf(vals[i][2], vals[i][3]));
#pragma unroll
    for (int o = 32; o > 0; o >>= 1) m = fmaxf(m, __shfl_down(m, o, 64));
    if (lane == 0) sred[i][wave] = m;
  }
  __syncthreads();
#pragma unroll
  for (int i = 0; i < 8; i++)
    mrow[i] = fmaxf(fmaxf(sred[i][0], sred[i][1]), fmaxf(sred[i][2], sred[i][3]));
  __syncthreads();
  // per-row expsum
#pragma unroll
  for (int i = 0; i < 8; i++) {
    float e = __expf(vals[i][0] - mrow[i]) + __expf(vals[i][1] - mrow[i])
            + __expf(vals[i][2] - mrow[i]) + __expf(vals[i][3] - mrow[i]);
#pragma unroll
    for (int o = 32; o > 0; o >>= 1) e += __shfl_down(e, o, 64);
    if (lane == 0) sred[i][wave] = e;
  }
  __syncthreads();
#pragma unroll
  for (int i = 0; i < 8; i++)
    lrow[i] = (sred[i][0] + sred[i][1]) + (sred[i][2] + sred[i][3]);
  if (!LAST) {
#pragma unroll
    for (int i = 0; i < 8; i++)
      if (tid == i) stats[b * N_ + s0 + i] = make_float2(mrow[i], 1.f / lrow[i]);
  } else {
#pragma unroll
    for (int i = 0; i < 8; i++) {
      float inv = 1.f / lrow[i];
      size_t rowoff = ((size_t)(b * N_ + s0 + i)) * N_;
#pragma unroll
      for (int tile = 0; tile < 4; tile++)
        SL[rowoff + tile * 256 + tid] = __expf(vals[i][tile] - mrow[i]) * inv;
    }
  }
}

__global__ __launch_bounds__(256) void upd_row8_0(
    float* __restrict__ Shat, const float* __restrict__ Ps, const float* __restrict__ Pt4,
    const float* __restrict__ bm1, const float* __restrict__ Wm2,
    const float* __restrict__ bm2, float2* __restrict__ stats) {
  upd_row8_body<0>(Shat, Ps, Pt4, bm1, Wm2, bm2, stats, nullptr);
}

__global__ __launch_bounds__(256) void upd_row8_1(
    float* __restrict__ Shat, const float* __restrict__ Ps, const float* __restrict__ Pt4,
    const float* __restrict__ bm1, const float* __restrict__ Wm2,
    const float* __restrict__ bm2, float* __restrict__ SL) {
  upd_row8_body<1>(Shat, Ps, Pt4, bm1, Wm2, bm2, nullptr, SL);
}

extern "C" void kernel_launch(void* const* d_in, const int* in_sizes, int n_in,
                              void* d_out, int out_size, void* d_ws, size_t ws_size,
                              hipStream_t stream) {
  const float* x_s = (const float*)d_in[0];
  const int*   ei_s = (const int*)d_in[1];
  const float* x_t = (const float*)d_in[2];
  const int*   ei_t = (const int*)d_in[3];
  const float* W1s = (const float*)d_in[4];
  const float* W1n = (const float*)d_in[5];
  const float* b1  = (const float*)d_in[6];
  const float* W2s = (const float*)d_in[7];
  const float* W2n = (const float*)d_in[8];
  const float* b2  = (const float*)d_in[9];
  const float* Wm1 = (const float*)d_in[10];
  const float* bm1 = (const float*)d_in[11];
  const float* Wm2 = (const float*)d_in[12];
  const float* bm2 = (const float*)d_in[13];
  const float* r_steps = (const float*)d_in[14];

  float* out = (float*)d_out;
  float* S0 = out;                         // [4,1024,1024]
  float* SL = out + (size_t)B_ * N_ * N_;  // [4,1024,1024]

  float* ws = (float*)d_ws;
  float* agg_s = ws;                       // 524288   (dead after psi1_gemm)
  float* agg_t = ws + 524288;              // 524288   (dead after psi1_gemm)
  float* h_s   = ws + 1048576;             // 524288   (dead after shat_gemm)
  float* h_t   = ws + 1572864;             // 524288   (dead after shat_gemm)
  float* part  = ws;                       // 2097152 floats = 8MB, reuses agg+h region
  float* Shat  = ws + 2097152;             // 4194304
  float* rtb   = ws + 6291456;             // 65536
  float2* stats = (float2*)(ws + 6356992); // 8192 floats (4096 float2)
  float* Ps    = ws + 6488064;             // 65536
  float* Pt4   = ws + 6553600;             // 65536 (layout [4][4096][4])
  int* counts  = (int*)(ws + 6619136);     // 8192
  int* cursor  = (int*)(ws + 6627328);     // 8192
  int* offs    = (int*)(ws + 6635520);     // 8194 (2 x 4097)
  int* csr     = (int*)(ws + 6643720);     // 131072

  // ---- CSR build: parallel 4-dispatch chain ----
  hipMemsetAsync(counts, 0, 2 * BN_ * sizeof(int), stream);
  hist_k<<<dim3(E_ / 256, 2), 256, 0, stream>>>(ei_s, ei_t, counts);
  csr_scan<<<2, 256, 0, stream>>>(counts, offs, cursor);
  csr_fill<<<dim3(E_ / 256, 2), 256, 0, stream>>>(ei_s, ei_t, cursor, csr);

  // ---- psi1 on both graphs ----
  gather_f<<<dim3(BN_ / 2, 2), 256, 0, stream>>>(x_s, x_t, csr, offs, agg_s, agg_t);
  psi1_gemm<<<dim3(2, 64, 2), 256, 0, stream>>>(x_s, agg_s, x_t, agg_t, W1s, W1n, b1, h_s, h_t);

  // ---- S_hat and S_0 ----
  shat_gemm<<<dim3(8, 8, 4), 256, 0, stream>>>(h_s, h_t, Shat);
  softmax_row<<<B_ * N_, 256, 0, stream>>>(Shat, S0);

  // ---- step 0 ----
  const float* rs0 = r_steps;
  rt_part_k<false><<<dim3(4, 32, 4), 256, 0, stream>>>(S0, nullptr, rs0, part);
  rt_reduce<<<64, 256, 0, stream>>>(part, rtb);
  gpsi2p<<<dim3(256, 2), 256, 0, stream>>>(rs0, rtb, csr, offs, W2s, W2n, b2, Wm1, Ps, Pt4);
  upd_row8_0<<<dim3(N_ / 8, B_), 256, 0, stream>>>(Shat, Ps, Pt4, bm1, Wm2, bm2, stats);

  // ---- step 1 (softmax fused into rt_part via stats; S_L written by upd_row8_1) ----
  const float* rs1 = r_steps + (size_t)B_ * N_ * R_;
  rt_part_k<true><<<dim3(4, 32, 4), 256, 0, stream>>>(Shat, stats, rs1, part);
  rt_reduce<<<64, 256, 0, stream>>>(part, rtb);
  gpsi2p<<<dim3(256, 2), 256, 0, stream>>>(rs1, rtb, csr, offs, W2s, W2n, b2, Wm1, Ps, Pt4);
  upd_row8_1<<<dim3(N_ / 8, B_), 256, 0, stream>>>(Shat, Ps, Pt4, bm1, Wm2, bm2, SL);
}